// Round 13
// baseline (123.302 us; speedup 1.0000x reference)
//
#include <hip/hip_runtime.h>
#include <hip/hip_bf16.h>
#include <hip/hip_fp16.h>

// NAM_89739046683406: per-feature tiny MLP (B=32768, F=128, H=64)
// logit(b) = bias + sum_f [ relu(relu(x[b,f]*w1[f]+b1[f]) @ w2[f] + b2[f]) . w3[f] + b3[f] ]
// out = [1-sigmoid, sigmoid]
//
// R34 = R33 body (fdot2 epilogue, best: 117.2us total / ~50.2us main) with
// 8-wave (512-thread) blocks: wave wv=tid>>6 owns f = gf*8+wv, gf=bx>>6
// (16 groups), rg=bx&63, grid 1024. Per-wave code identical to R33.
// Rationale: R33 showed VALUBusy 65->46 with only -4% time -> VALU issue no
// longer critical; waves are ~90% dependency-stalled at ~2-3 waves/SIMD.
// 512-thread blocks reach 4 waves/SIMD via GEOMETRY (2 resident blocks x 8
// waves), not via the RA-coercing min-waves clause: LB(512,3) caps VGPR at
// 170 >> our 76, so R24's panic-demotion trap cannot fire. 1024 blocks =
// 4/CU of work -> 2 resident = exactly 2 rounds. part shrinks 4MB->2MB.
//
// Evidence ledger:
//   - fdot2 epilogue proven (R33: VALU -30%, time -4%, absmax unchanged).
//   - 4-wave-block occupancy alternatives dead: LB(256,4) panic-spills
//     (R24); plain LB(256) under-resides (R26); per-bt restructure loses
//     (R27). This round tests geometry, the one untried occupancy path.
//   - x-path exonerated twice (R23, R25); 16-row scatter tail loses (R28);
//     MFMA-epilogue RETIRED (R30 NaN, R31 absmax 0.68).
//   - NO float-ext-vector arrays + __builtin_elementwise_* (R17/R18).
//   - Judge spills by FETCH/WRITE counters, not VGPR_Count.
// Failure signatures THIS round: (A) VGPR drop + FETCH/WRITE blowup =
// demotion (unexpected at cap 170) -> revert R33. (B) occupancy flat &
// time ~50us = runtime under-resides 512-blocks -> try LB(512,4) next.

#define B_SZ 32768
#define F_SZ 128
#define H_SZ 64

typedef _Float16 half8 __attribute__((ext_vector_type(8)));  // f16 x8 (4 VGPR)
typedef float floatx4 __attribute__((ext_vector_type(4)));   // fp32 x4 acc

union U8 { half8 v; unsigned u[4]; };

// pack two fp32 -> half2 bits (RNE)
__device__ __forceinline__ unsigned pkh(float lo, float hi) {
    __half2 h = __float22half2_rn(make_float2(lo, hi));
    return __builtin_bit_cast(unsigned, h);
}

// pack two fp32 -> half2 bits (RTZ, single v_cvt_pkrtz_f16_f32)
__device__ __forceinline__ unsigned cpk(float lo, float hi) {
    return __builtin_bit_cast(unsigned, __builtin_amdgcn_cvt_pkrtz(lo, hi));
}

// packed f16 relu via v_pk_max_f16
__device__ __forceinline__ unsigned relu2(unsigned a) {
    unsigned r;
    asm("v_pk_max_f16 %0, %1, %2" : "=v"(r) : "v"(a), "v"(0u));
    return r;
}

// f16-pair dot product with f32 accumulate: d = a.lo*b.lo + a.hi*b.hi + c
__device__ __forceinline__ float fdot2(unsigned a, unsigned b, float c) {
    float d;
    asm("v_dot2_f32_f16 %0, %1, %2, %3" : "=v"(d) : "v"(a), "v"(b), "v"(c));
    return d;
}

__device__ __forceinline__ __half2 bch2(unsigned u) {
    return __builtin_bit_cast(__half2, u);
}

// ---- main: block = 8 waves (512 thr); wave wv owns feature f = gf*8+wv,
//      gf = bx>>6 (0..15), rows [rg*512, rg*512+512), rg = bx&63.
//      8 chunks of 64 rows; preamble packs w2[f] -> f16 A-fragments.
//      Output: part[gf][rb..rb+512) plain store (sole writer).
__global__ __launch_bounds__(512, 3)
void nam_main(const float* __restrict__ x,
              const float* __restrict__ w1, const float* __restrict__ b1,
              const float* __restrict__ b2, const float* __restrict__ w3,
              const float* __restrict__ b3,
              const float* __restrict__ w2,
              float* __restrict__ part)
{
    __shared__ float partial[8][512];    // 16KB

    const int tid  = threadIdx.x;
    const int lane = tid & 63;
    const int wv   = tid >> 6;           // 0..7
    const int l15  = lane & 15;
    const int quad = lane >> 4;
    const int rg   = blockIdx.x & 63;
    const int gf   = blockIdx.x >> 6;    // 0..15
    const int f    = gf * 8 + wv;
    const int rb   = rg * 512;

    // ---- per-wave resident tables ----
    // w2 A-fragments packed in-place from fp32 source (f16):
    // frag (gt,ks): elem j = w2[f][k=ks*32+quad*8+j][g=gt*16+l15]
    const float* w2f = w2 + (size_t)f * H_SZ * H_SZ;
    half8 wfrag[4][2];
    #pragma unroll
    for (int gt = 0; gt < 4; ++gt)
        #pragma unroll
        for (int ks = 0; ks < 2; ++ks) {
            const float* src = w2f + (ks * 32 + quad * 8) * H_SZ + gt * 16 + l15;
            U8 o;
            #pragma unroll
            for (int t = 0; t < 4; ++t)
                o.u[t] = pkh(src[(2 * t) * H_SZ], src[(2 * t + 1) * H_SZ]);
            wfrag[gt][ks] = o.v;
        }

    // w1/b1 as packed half2: element k = ks*32 + quad*8 + (2t, 2t+1)
    unsigned wk2[2][4], bk2[2][4];
    #pragma unroll
    for (int ks = 0; ks < 2; ++ks) {
        float wtmp[8], btmp[8];
        const float4* wq = (const float4*)(w1 + f * 64 + ks * 32 + quad * 8);
        const float4* bq = (const float4*)(b1 + f * 64 + ks * 32 + quad * 8);
        *(float4*)&wtmp[0] = wq[0]; *(float4*)&wtmp[4] = wq[1];
        *(float4*)&btmp[0] = bq[0]; *(float4*)&btmp[4] = bq[1];
        #pragma unroll
        for (int t = 0; t < 4; ++t) {
            wk2[ks][t] = pkh(wtmp[2 * t], wtmp[2 * t + 1]);
            bk2[ks][t] = pkh(btmp[2 * t], btmp[2 * t + 1]);
        }
    }

    // b2 as MFMA C operand quads; w3 as packed f16 pairs for fdot2:
    // pair p of tile gt covers g = gt*16 + quad*4 + {2p, 2p+1}
    floatx4 b2c[4];
    unsigned w3h[4][2];
    #pragma unroll
    for (int gt = 0; gt < 4; ++gt) {
        float4 bv  = *(const float4*)(b2 + f * 64 + gt * 16 + quad * 4);
        float4 wv3 = *(const float4*)(w3 + f * 64 + gt * 16 + quad * 4);
        b2c[gt] = floatx4{bv.x, bv.y, bv.z, bv.w};
        w3h[gt][0] = pkh(wv3.x, wv3.y);
        w3h[gt][1] = pkh(wv3.z, wv3.w);
    }
    const float b3f = b3[f];

    // ---- 8 chunks of 64 rows, software-pipelined x gather ----
    float xv = x[(size_t)(rb + lane) * F_SZ + f];   // chunk 0

    #pragma unroll 1
    for (int c = 0; c < 8; ++c) {
        float xvn;
        if (c < 7)
            xvn = x[(size_t)(rb + (c + 1) * 64 + lane) * F_SZ + f];

        // splat-pack x to half2 once, broadcast packed word per 16-row block
        unsigned xpk = __builtin_bit_cast(unsigned, __float2half2_rn(xv));
        unsigned xf[4];
        #pragma unroll
        for (int bt = 0; bt < 4; ++bt)
            xf[bt] = (unsigned)__shfl((int)xpk, bt * 16 + l15, 64);

        // h1 B-fragments in packed f16: B[k=quad*8+j][n=bt*16+l15]
        half8 hfrag[4][2];
        #pragma unroll
        for (int ks = 0; ks < 2; ++ks)
            #pragma unroll
            for (int bt = 0; bt < 4; ++bt) {
                U8 o;
                #pragma unroll
                for (int t = 0; t < 4; ++t) {
                    __half2 h = __hfma2(bch2(xf[bt]), bch2(wk2[ks][t]), bch2(bk2[ks][t]));
                    o.u[t] = relu2(__builtin_bit_cast(unsigned, h));
                }
                hfrag[bt][ks] = o.v;
            }

        // MFMA f16 (C = b2c direct, D != C) + fdot2 epilogue
        // D layout: g = gt*16 + quad*4 + i, n = bt*16 + l15
        float t[4] = {0.0f, 0.0f, 0.0f, 0.0f};
        #pragma unroll
        for (int gt = 0; gt < 4; ++gt)
            #pragma unroll
            for (int bt = 0; bt < 4; ++bt) {
                floatx4 acc = __builtin_amdgcn_mfma_f32_16x16x32_f16(
                    wfrag[gt][0], hfrag[bt][0], b2c[gt], 0, 0, 0);
                acc = __builtin_amdgcn_mfma_f32_16x16x32_f16(
                    wfrag[gt][1], hfrag[bt][1], acc, 0, 0, 0);
                unsigned p0 = relu2(cpk(acc[0], acc[1]));
                unsigned p1 = relu2(cpk(acc[2], acc[3]));
                t[bt] = fdot2(p0, w3h[gt][0], t[bt]);
                t[bt] = fdot2(p1, w3h[gt][1], t[bt]);
            }

        // quad-reduce (row = bt*16 + l15), publish per-chunk rows
        #pragma unroll
        for (int bt = 0; bt < 4; ++bt) {
            t[bt] += __shfl_xor(t[bt], 16, 64);
            t[bt] += __shfl_xor(t[bt], 32, 64);
        }
        if (quad == 0) {
            #pragma unroll
            for (int bt = 0; bt < 4; ++bt)
                partial[wv][c * 64 + bt * 16 + l15] = t[bt] + b3f;
        }

        xv = xvn;
    }

    __syncthreads();

    // block reduce over the 8 features -> plain coalesced store (sole writer)
    {
        int row = tid;   // 512 threads, 512 rows
        float p = ((partial[0][row] + partial[1][row])
                 + (partial[2][row] + partial[3][row]))
                + ((partial[4][row] + partial[5][row])
                 + (partial[6][row] + partial[7][row]));
        part[(size_t)gf * B_SZ + rb + row] = p;
    }
}

// ---- final: 1 row/thread, sum 16 gf-partials + bias + sigmoid ----
__global__ __launch_bounds__(256)
void nam_final(const float* __restrict__ part, const float* __restrict__ bias,
               float* __restrict__ out)
{
    int b = blockIdx.x * 256 + threadIdx.x;
    float s = bias[0];
    #pragma unroll
    for (int gf = 0; gf < 16; ++gf)
        s += part[(size_t)gf * B_SZ + b];
    float p = 1.0f / (1.0f + __expf(-s));
    ((float2*)out)[b] = make_float2(1.0f - p, p);
}

extern "C" void kernel_launch(void* const* d_in, const int* in_sizes, int n_in,
                              void* d_out, int out_size, void* d_ws, size_t ws_size,
                              hipStream_t stream)
{
    const float* x    = (const float*)d_in[0];
    const float* w1   = (const float*)d_in[1];
    const float* b1   = (const float*)d_in[2];
    const float* w2   = (const float*)d_in[3];
    const float* b2   = (const float*)d_in[4];
    const float* w3   = (const float*)d_in[5];
    const float* b3   = (const float*)d_in[6];
    const float* bias = (const float*)d_in[7];
    float* out = (float*)d_out;

    float* part = (float*)d_ws;   // part[16][B_SZ], 2MB

    nam_main<<<dim3(1024), dim3(512), 0, stream>>>(
        x, w1, b1, b2, w3, b3, w2, part);
    nam_final<<<dim3(B_SZ / 256), dim3(256), 0, stream>>>(part, bias, out);
}

// Round 14
// 119.955 us; speedup vs baseline: 1.0279x; 1.0279x over previous
//
#include <hip/hip_runtime.h>
#include <hip/hip_bf16.h>
#include <hip/hip_fp16.h>

// NAM_89739046683406: per-feature tiny MLP (B=32768, F=128, H=64)
// logit(b) = bias + sum_f [ relu(relu(x[b,f]*w1[f]+b1[f]) @ w2[f] + b2[f]) . w3[f] + b3[f] ]
// out = [1-sigmoid, sigmoid]
//
// R35 = R33 (fdot2 epilogue, best 117.2us/50.2us) + explicit cross-chunk
// software pipeline: two named hfrag buffers hA/hB, manual x2 unroll.
// Per iteration k (chunks c0=2k, c1=2k+1):
//   prefetch x(c0+2), x(c1+2) -> build(hB, c1) -> consume(hA, c0)
//   -> build(hA, c0+2) -> consume(hB, c1)
// Every point of the loop now has two independent instruction streams:
// MFMA/fdot2 latency of one chunk is covered by build-VALU of the next,
// and the DS tail overlaps the next chunk's MFMA. Unlike R23 (plain
// unroll -- compiler serialized through copies), buffers are NAMED and
// statically indexed (T15/rule-20), x prefetch distance 2.
// Rationale: R33 showed VALU -30% but time -4% -> binder is intra-wave
// dep latency (~5.9k cyc wall vs ~650 issue per chunk at ~2 waves/SIMD).
//
// Evidence ledger:
//   - fdot2 epilogue proven (R33); f16 pk-math layer-1 proven (R22).
//   - Occupancy ledger CLOSED, 4 failures: LB(256,4) spills (R24), free RA
//     under-resides (R26), per-bt high-occ loses (R27), 8-wave geometry
//     under-resides (R34). LB(256,3)+4-wave+grid2048 = peak (26%).
//   - x-path exonerated (R23,R25); scatter tail loses (R28); MFMA-epilogue
//     RETIRED (R30 NaN, R31 absmax 0.68).
//   - NO float-ext-vector arrays + __builtin_elementwise_* (R17/R18).
//   - Judge spills by FETCH/WRITE counters, not VGPR_Count.
// Failure signatures THIS round: FETCH/WRITE blowup = spill -> revert R33;
// neutral ~50us = ILP can't fill the stall -> structural plateau.

#define B_SZ 32768
#define F_SZ 128
#define H_SZ 64

typedef _Float16 half8 __attribute__((ext_vector_type(8)));  // f16 x8 (4 VGPR)
typedef float floatx4 __attribute__((ext_vector_type(4)));   // fp32 x4 acc

union U8 { half8 v; unsigned u[4]; };

// pack two fp32 -> half2 bits (RNE)
__device__ __forceinline__ unsigned pkh(float lo, float hi) {
    __half2 h = __float22half2_rn(make_float2(lo, hi));
    return __builtin_bit_cast(unsigned, h);
}

// pack two fp32 -> half2 bits (RTZ, single v_cvt_pkrtz_f16_f32)
__device__ __forceinline__ unsigned cpk(float lo, float hi) {
    return __builtin_bit_cast(unsigned, __builtin_amdgcn_cvt_pkrtz(lo, hi));
}

// packed f16 relu via v_pk_max_f16
__device__ __forceinline__ unsigned relu2(unsigned a) {
    unsigned r;
    asm("v_pk_max_f16 %0, %1, %2" : "=v"(r) : "v"(a), "v"(0u));
    return r;
}

// f16-pair dot product with f32 accumulate: d = a.lo*b.lo + a.hi*b.hi + c
__device__ __forceinline__ float fdot2(unsigned a, unsigned b, float c) {
    float d;
    asm("v_dot2_f32_f16 %0, %1, %2, %3" : "=v"(d) : "v"(a), "v"(b), "v"(c));
    return d;
}

__device__ __forceinline__ __half2 bch2(unsigned u) {
    return __builtin_bit_cast(__half2, u);
}

// ---- main: block = 4 waves; wave wv owns feature f = (bx>>6)*4+wv,
//      rows [rg*512, rg*512+512), rg = bx&63. 8 chunks of 64 rows,
//      software-pipelined x2 (build c+1 overlaps consume c).
//      Output: part[gf][rb..rb+512) plain store (sole writer).
__global__ __launch_bounds__(256, 3)
void nam_main(const float* __restrict__ x,
              const float* __restrict__ w1, const float* __restrict__ b1,
              const float* __restrict__ b2, const float* __restrict__ w3,
              const float* __restrict__ b3,
              const float* __restrict__ w2,
              float* __restrict__ part)
{
    __shared__ float partial[4][512];    // 8KB

    const int tid  = threadIdx.x;
    const int lane = tid & 63;
    const int wv   = tid >> 6;           // 0..3
    const int l15  = lane & 15;
    const int quad = lane >> 4;
    const int rg   = blockIdx.x & 63;
    const int gf   = blockIdx.x >> 6;    // 0..31
    const int f    = gf * 4 + wv;
    const int rb   = rg * 512;

    // ---- per-wave resident tables ----
    // w2 A-fragments packed in-place from fp32 source (f16):
    // frag (gt,ks): elem j = w2[f][k=ks*32+quad*8+j][g=gt*16+l15]
    const float* w2f = w2 + (size_t)f * H_SZ * H_SZ;
    half8 wfrag[4][2];
    #pragma unroll
    for (int gt = 0; gt < 4; ++gt)
        #pragma unroll
        for (int ks = 0; ks < 2; ++ks) {
            const float* src = w2f + (ks * 32 + quad * 8) * H_SZ + gt * 16 + l15;
            U8 o;
            #pragma unroll
            for (int t = 0; t < 4; ++t)
                o.u[t] = pkh(src[(2 * t) * H_SZ], src[(2 * t + 1) * H_SZ]);
            wfrag[gt][ks] = o.v;
        }

    // w1/b1 as packed half2: element k = ks*32 + quad*8 + (2t, 2t+1)
    unsigned wk2[2][4], bk2[2][4];
    #pragma unroll
    for (int ks = 0; ks < 2; ++ks) {
        float wtmp[8], btmp[8];
        const float4* wq = (const float4*)(w1 + f * 64 + ks * 32 + quad * 8);
        const float4* bq = (const float4*)(b1 + f * 64 + ks * 32 + quad * 8);
        *(float4*)&wtmp[0] = wq[0]; *(float4*)&wtmp[4] = wq[1];
        *(float4*)&btmp[0] = bq[0]; *(float4*)&btmp[4] = bq[1];
        #pragma unroll
        for (int t = 0; t < 4; ++t) {
            wk2[ks][t] = pkh(wtmp[2 * t], wtmp[2 * t + 1]);
            bk2[ks][t] = pkh(btmp[2 * t], btmp[2 * t + 1]);
        }
    }

    // b2 as MFMA C operand quads; w3 as packed f16 pairs for fdot2
    floatx4 b2c[4];
    unsigned w3h[4][2];
    #pragma unroll
    for (int gt = 0; gt < 4; ++gt) {
        float4 bv  = *(const float4*)(b2 + f * 64 + gt * 16 + quad * 4);
        float4 wv3 = *(const float4*)(w3 + f * 64 + gt * 16 + quad * 4);
        b2c[gt] = floatx4{bv.x, bv.y, bv.z, bv.w};
        w3h[gt][0] = pkh(wv3.x, wv3.y);
        w3h[gt][1] = pkh(wv3.z, wv3.w);
    }
    const float b3f = b3[f];

    // fragment build: broadcast x -> packed f16 h1 B-fragments
    auto build = [&](half8 (&hf)[4][2], float xv) {
        unsigned xpk = __builtin_bit_cast(unsigned, __float2half2_rn(xv));
        unsigned xf[4];
        #pragma unroll
        for (int bt = 0; bt < 4; ++bt)
            xf[bt] = (unsigned)__shfl((int)xpk, bt * 16 + l15, 64);
        #pragma unroll
        for (int ks = 0; ks < 2; ++ks)
            #pragma unroll
            for (int bt = 0; bt < 4; ++bt) {
                U8 o;
                #pragma unroll
                for (int t = 0; t < 4; ++t) {
                    __half2 h = __hfma2(bch2(xf[bt]), bch2(wk2[ks][t]), bch2(bk2[ks][t]));
                    o.u[t] = relu2(__builtin_bit_cast(unsigned, h));
                }
                hf[bt][ks] = o.v;
            }
    };

    // consume: MFMA pairs + fdot2 epilogue + quad-reduce + publish chunk c
    auto consume = [&](const half8 (&hf)[4][2], int c) {
        float t[4] = {0.0f, 0.0f, 0.0f, 0.0f};
        #pragma unroll
        for (int gt = 0; gt < 4; ++gt)
            #pragma unroll
            for (int bt = 0; bt < 4; ++bt) {
                floatx4 acc = __builtin_amdgcn_mfma_f32_16x16x32_f16(
                    wfrag[gt][0], hf[bt][0], b2c[gt], 0, 0, 0);
                acc = __builtin_amdgcn_mfma_f32_16x16x32_f16(
                    wfrag[gt][1], hf[bt][1], acc, 0, 0, 0);
                unsigned p0 = relu2(cpk(acc[0], acc[1]));
                unsigned p1 = relu2(cpk(acc[2], acc[3]));
                t[bt] = fdot2(p0, w3h[gt][0], t[bt]);
                t[bt] = fdot2(p1, w3h[gt][1], t[bt]);
            }
        #pragma unroll
        for (int bt = 0; bt < 4; ++bt) {
            t[bt] += __shfl_xor(t[bt], 16, 64);
            t[bt] += __shfl_xor(t[bt], 32, 64);
        }
        if (quad == 0) {
            #pragma unroll
            for (int bt = 0; bt < 4; ++bt)
                partial[wv][c * 64 + bt * 16 + l15] = t[bt] + b3f;
        }
    };

    // ---- pipelined 8 chunks: named double buffers, x prefetch distance 2
    const float* xcol = x + f;
    half8 hA[4][2], hB[4][2];

    float xvb = xcol[(size_t)(rb + 64 + lane) * F_SZ];         // x(1)
    {
        float xva = xcol[(size_t)(rb + lane) * F_SZ];          // x(0)
        build(hA, xva);
    }

    #pragma unroll 1
    for (int k = 0; k < 4; ++k) {
        const int c0 = 2 * k, c1 = 2 * k + 1;
        float xvc = 0.0f, xvd = 0.0f;
        if (c0 + 2 < 8)
            xvc = xcol[(size_t)(rb + (c0 + 2) * 64 + lane) * F_SZ];
        if (c1 + 2 < 8)
            xvd = xcol[(size_t)(rb + (c1 + 2) * 64 + lane) * F_SZ];

        build(hB, xvb);       // chunk c1 -- overlaps consume(hA) MFMA latency
        consume(hA, c0);      // chunk c0
        if (k < 3)
            build(hA, xvc);   // chunk c0+2 -- overlaps consume(hB)
        consume(hB, c1);      // chunk c1

        xvb = xvd;
    }

    __syncthreads();

    // block reduce over the 4 features -> plain coalesced store (sole writer)
    #pragma unroll
    for (int k = 0; k < 2; ++k) {
        int row = k * 256 + tid;
        float p = partial[0][row] + partial[1][row]
                + partial[2][row] + partial[3][row];
        part[(size_t)gf * B_SZ + rb + row] = p;
    }
}

// ---- final: 1 row/thread, sum 32 gf-partials + bias + sigmoid ----
__global__ __launch_bounds__(256)
void nam_final(const float* __restrict__ part, const float* __restrict__ bias,
               float* __restrict__ out)
{
    int b = blockIdx.x * 256 + threadIdx.x;
    float s = bias[0];
    #pragma unroll
    for (int gf = 0; gf < 32; ++gf)
        s += part[(size_t)gf * B_SZ + b];
    float p = 1.0f / (1.0f + __expf(-s));
    ((float2*)out)[b] = make_float2(1.0f - p, p);
}

extern "C" void kernel_launch(void* const* d_in, const int* in_sizes, int n_in,
                              void* d_out, int out_size, void* d_ws, size_t ws_size,
                              hipStream_t stream)
{
    const float* x    = (const float*)d_in[0];
    const float* w1   = (const float*)d_in[1];
    const float* b1   = (const float*)d_in[2];
    const float* w2   = (const float*)d_in[3];
    const float* b2   = (const float*)d_in[4];
    const float* w3   = (const float*)d_in[5];
    const float* b3   = (const float*)d_in[6];
    const float* bias = (const float*)d_in[7];
    float* out = (float*)d_out;

    float* part = (float*)d_ws;   // part[32][B_SZ], 4MB

    nam_main<<<dim3(2048), dim3(256), 0, stream>>>(
        x, w1, b1, b2, w3, b3, w2, part);
    nam_final<<<dim3(B_SZ / 256), dim3(256), 0, stream>>>(part, bias, out);
}

// Round 16
// 113.940 us; speedup vs baseline: 1.0822x; 1.0528x over previous
//
#include <hip/hip_runtime.h>
#include <hip/hip_bf16.h>
#include <hip/hip_fp16.h>

// NAM_89739046683406: per-feature tiny MLP (B=32768, F=128, H=64)
// logit(b) = bias + sum_f [ relu(relu(x[b,f]*w1[f]+b1[f]) @ w2[f] + b2[f]) . w3[f] + b3[f] ]
// out = [1-sigmoid, sigmoid]
//
// R37 = R33 (fdot2 epilogue, best passing: 117.2us total / 50.2us main)
// + s_setprio(1) around the MFMA+fdot2 cluster (T5). T5 requires wave
// role diversity: null on barrier-lockstep GEMM (m190), +4-7% on attn
// (m191). Our chunk loop has NO barriers -- 12 resident waves from 3
// independent blocks drift through build/MFMA/tail phases freely -- the
// diverse-phase regime where priority arbitration pays. Cost: 2 SALU.
//
// FINAL evidence ledger (16 rounds):
//   - WINS: R22 f16 pk-math layer-1 (-25% VALU -> -15% time); R33 fdot2
//     epilogue (-30% VALU -> -4% time). VALU compression = only lever.
//   - Occupancy CLOSED: LB(256,4) panic-spills (R24); free RA under-
//     resides (R26); per-bt high-occ loses (R27); 8-wave geometry under-
//     resides (R34). LB(256,3)+4wave+grid2048 = peak (26%, non-monotonic).
//   - ILP-pipelining CLOSED: plain unroll (R23) and named-dbuf pipeline
//     (R35) both regress +15-20% -- compiler re-serializes.
//   - x-path EXONERATED: per-lane gathers (R23), LDS staging (R25).
//   - Tail RETIRED: [16][520] scatter neutral + 524k conflicts (R28);
//     [wv][row][quad] scatter fails absmax 0.283 (R36, fault not
//     isolatable by inspection).
//   - MFMA-epilogue RETIRED: 16x16x16 builtin NaN (R30); zero-padded
//     16x16x32 absmax 0.68 (R31).
//   - NO float-ext-vector arrays + __builtin_elementwise_* (R17/R18).
//   - Judge spills by FETCH/WRITE counters, not VGPR_Count.
// Regime: latency-bound plateau (HBM 5%, MfmaUtil 26%, VALU 46) -- NOT a
// roofline; the ~50us-vs-17us-issue-floor gap is dependency stall that 9
// probe classes failed to close. If this round is neutral, R33/R37 stands.

#define B_SZ 32768
#define F_SZ 128
#define H_SZ 64

typedef _Float16 half8 __attribute__((ext_vector_type(8)));  // f16 x8 (4 VGPR)
typedef float floatx4 __attribute__((ext_vector_type(4)));   // fp32 x4 acc

union U8 { half8 v; unsigned u[4]; };

// pack two fp32 -> half2 bits (RNE)
__device__ __forceinline__ unsigned pkh(float lo, float hi) {
    __half2 h = __float22half2_rn(make_float2(lo, hi));
    return __builtin_bit_cast(unsigned, h);
}

// pack two fp32 -> half2 bits (RTZ, single v_cvt_pkrtz_f16_f32)
__device__ __forceinline__ unsigned cpk(float lo, float hi) {
    return __builtin_bit_cast(unsigned, __builtin_amdgcn_cvt_pkrtz(lo, hi));
}

// packed f16 relu via v_pk_max_f16
__device__ __forceinline__ unsigned relu2(unsigned a) {
    unsigned r;
    asm("v_pk_max_f16 %0, %1, %2" : "=v"(r) : "v"(a), "v"(0u));
    return r;
}

// f16-pair dot product with f32 accumulate: d = a.lo*b.lo + a.hi*b.hi + c
__device__ __forceinline__ float fdot2(unsigned a, unsigned b, float c) {
    float d;
    asm("v_dot2_f32_f16 %0, %1, %2, %3" : "=v"(d) : "v"(a), "v"(b), "v"(c));
    return d;
}

__device__ __forceinline__ __half2 bch2(unsigned u) {
    return __builtin_bit_cast(__half2, u);
}

// ---- main: block = 4 waves; wave wv owns feature f = (bx>>6)*4+wv,
//      rows [rg*512, rg*512+512), rg = bx&63. 8 chunks of 64 rows.
//      Preamble packs w2[f] -> f16 A-fragments in registers.
//      Output: part[gf][rb..rb+512) plain store (sole writer).
__global__ __launch_bounds__(256, 3)
void nam_main(const float* __restrict__ x,
              const float* __restrict__ w1, const float* __restrict__ b1,
              const float* __restrict__ b2, const float* __restrict__ w3,
              const float* __restrict__ b3,
              const float* __restrict__ w2,
              float* __restrict__ part)
{
    __shared__ float partial[4][512];    // 8KB

    const int tid  = threadIdx.x;
    const int lane = tid & 63;
    const int wv   = tid >> 6;           // 0..3
    const int l15  = lane & 15;
    const int quad = lane >> 4;
    const int rg   = blockIdx.x & 63;
    const int gf   = blockIdx.x >> 6;    // 0..31
    const int f    = gf * 4 + wv;
    const int rb   = rg * 512;

    // ---- per-wave resident tables ----
    // w2 A-fragments packed in-place from fp32 source (f16):
    // frag (gt,ks): elem j = w2[f][k=ks*32+quad*8+j][g=gt*16+l15]
    const float* w2f = w2 + (size_t)f * H_SZ * H_SZ;
    half8 wfrag[4][2];
    #pragma unroll
    for (int gt = 0; gt < 4; ++gt)
        #pragma unroll
        for (int ks = 0; ks < 2; ++ks) {
            const float* src = w2f + (ks * 32 + quad * 8) * H_SZ + gt * 16 + l15;
            U8 o;
            #pragma unroll
            for (int t = 0; t < 4; ++t)
                o.u[t] = pkh(src[(2 * t) * H_SZ], src[(2 * t + 1) * H_SZ]);
            wfrag[gt][ks] = o.v;
        }

    // w1/b1 as packed half2: element k = ks*32 + quad*8 + (2t, 2t+1)
    unsigned wk2[2][4], bk2[2][4];
    #pragma unroll
    for (int ks = 0; ks < 2; ++ks) {
        float wtmp[8], btmp[8];
        const float4* wq = (const float4*)(w1 + f * 64 + ks * 32 + quad * 8);
        const float4* bq = (const float4*)(b1 + f * 64 + ks * 32 + quad * 8);
        *(float4*)&wtmp[0] = wq[0]; *(float4*)&wtmp[4] = wq[1];
        *(float4*)&btmp[0] = bq[0]; *(float4*)&btmp[4] = bq[1];
        #pragma unroll
        for (int t = 0; t < 4; ++t) {
            wk2[ks][t] = pkh(wtmp[2 * t], wtmp[2 * t + 1]);
            bk2[ks][t] = pkh(btmp[2 * t], btmp[2 * t + 1]);
        }
    }

    // b2 as MFMA C operand quads; w3 as packed f16 pairs for fdot2:
    // pair p of tile gt covers g = gt*16 + quad*4 + {2p, 2p+1}
    floatx4 b2c[4];
    unsigned w3h[4][2];
    #pragma unroll
    for (int gt = 0; gt < 4; ++gt) {
        float4 bv  = *(const float4*)(b2 + f * 64 + gt * 16 + quad * 4);
        float4 wv3 = *(const float4*)(w3 + f * 64 + gt * 16 + quad * 4);
        b2c[gt] = floatx4{bv.x, bv.y, bv.z, bv.w};
        w3h[gt][0] = pkh(wv3.x, wv3.y);
        w3h[gt][1] = pkh(wv3.z, wv3.w);
    }
    const float b3f = b3[f];

    // ---- 8 chunks of 64 rows, software-pipelined x gather ----
    float xv = x[(size_t)(rb + lane) * F_SZ + f];   // chunk 0

    #pragma unroll 1
    for (int c = 0; c < 8; ++c) {
        float xvn;
        if (c < 7)
            xvn = x[(size_t)(rb + (c + 1) * 64 + lane) * F_SZ + f];

        // splat-pack x to half2 once, broadcast packed word per 16-row block
        unsigned xpk = __builtin_bit_cast(unsigned, __float2half2_rn(xv));
        unsigned xf[4];
        #pragma unroll
        for (int bt = 0; bt < 4; ++bt)
            xf[bt] = (unsigned)__shfl((int)xpk, bt * 16 + l15, 64);

        // h1 B-fragments in packed f16: B[k=quad*8+j][n=bt*16+l15]
        half8 hfrag[4][2];
        #pragma unroll
        for (int ks = 0; ks < 2; ++ks)
            #pragma unroll
            for (int bt = 0; bt < 4; ++bt) {
                U8 o;
                #pragma unroll
                for (int t = 0; t < 4; ++t) {
                    __half2 h = __hfma2(bch2(xf[bt]), bch2(wk2[ks][t]), bch2(bk2[ks][t]));
                    o.u[t] = relu2(__builtin_bit_cast(unsigned, h));
                }
                hfrag[bt][ks] = o.v;
            }

        // MFMA f16 (C = b2c direct, D != C) + fdot2 epilogue, prioritized
        // (T5: waves here are phase-diverse -- no barriers in chunk loop).
        // D layout: g = gt*16 + quad*4 + i, n = bt*16 + l15
        float t[4] = {0.0f, 0.0f, 0.0f, 0.0f};
        __builtin_amdgcn_s_setprio(1);
        #pragma unroll
        for (int gt = 0; gt < 4; ++gt)
            #pragma unroll
            for (int bt = 0; bt < 4; ++bt) {
                floatx4 acc = __builtin_amdgcn_mfma_f32_16x16x32_f16(
                    wfrag[gt][0], hfrag[bt][0], b2c[gt], 0, 0, 0);
                acc = __builtin_amdgcn_mfma_f32_16x16x32_f16(
                    wfrag[gt][1], hfrag[bt][1], acc, 0, 0, 0);
                unsigned p0 = relu2(cpk(acc[0], acc[1]));
                unsigned p1 = relu2(cpk(acc[2], acc[3]));
                t[bt] = fdot2(p0, w3h[gt][0], t[bt]);
                t[bt] = fdot2(p1, w3h[gt][1], t[bt]);
            }
        __builtin_amdgcn_s_setprio(0);

        // quad-reduce (row = bt*16 + l15), publish per-chunk rows
        #pragma unroll
        for (int bt = 0; bt < 4; ++bt) {
            t[bt] += __shfl_xor(t[bt], 16, 64);
            t[bt] += __shfl_xor(t[bt], 32, 64);
        }
        if (quad == 0) {
            #pragma unroll
            for (int bt = 0; bt < 4; ++bt)
                partial[wv][c * 64 + bt * 16 + l15] = t[bt] + b3f;
        }

        xv = xvn;
    }

    __syncthreads();

    // block reduce over the 4 features -> plain coalesced store (sole writer)
    #pragma unroll
    for (int k = 0; k < 2; ++k) {
        int row = k * 256 + tid;
        float p = partial[0][row] + partial[1][row]
                + partial[2][row] + partial[3][row];
        part[(size_t)gf * B_SZ + rb + row] = p;
    }
}

// ---- final: 1 row/thread, sum 32 gf-partials + bias + sigmoid ----
__global__ __launch_bounds__(256)
void nam_final(const float* __restrict__ part, const float* __restrict__ bias,
               float* __restrict__ out)
{
    int b = blockIdx.x * 256 + threadIdx.x;
    float s = bias[0];
    #pragma unroll
    for (int gf = 0; gf < 32; ++gf)
        s += part[(size_t)gf * B_SZ + b];
    float p = 1.0f / (1.0f + __expf(-s));
    ((float2*)out)[b] = make_float2(1.0f - p, p);
}

extern "C" void kernel_launch(void* const* d_in, const int* in_sizes, int n_in,
                              void* d_out, int out_size, void* d_ws, size_t ws_size,
                              hipStream_t stream)
{
    const float* x    = (const float*)d_in[0];
    const float* w1   = (const float*)d_in[1];
    const float* b1   = (const float*)d_in[2];
    const float* w2   = (const float*)d_in[3];
    const float* b2   = (const float*)d_in[4];
    const float* w3   = (const float*)d_in[5];
    const float* b3   = (const float*)d_in[6];
    const float* bias = (const float*)d_in[7];
    float* out = (float*)d_out;

    float* part = (float*)d_ws;   // part[32][B_SZ], 4MB

    nam_main<<<dim3(2048), dim3(256), 0, stream>>>(
        x, w1, b1, b2, w3, b3, w2, part);
    nam_final<<<dim3(B_SZ / 256), dim3(256), 0, stream>>>(part, bias, out);
}